// Round 2
// baseline (503.868 us; speedup 1.0000x reference)
//
#include <hip/hip_runtime.h>
#include <hip/hip_bf16.h>
#include <cstdint>

#define NB    8
#define NPTS  4096
#define NQ    4              // col-quarters (blockIdx.y)
#define NT    64             // cand tiles per quarter (1024/16)
#define PROW  64             // part row stride in u32 (4 quarters x 16)
#define SENT  0xFF000000u    // sentinel key (> any real positive-float key)

typedef __attribute__((ext_vector_type(8))) short bf16x8;
typedef __attribute__((ext_vector_type(4))) float f32x4;

// ---------------------------------------------------------------------------
// A: x [B,C,N] -> XT fp32 [B,N,64], XH/XL bf16 split, sq, sqn=0.5*sq.
// Fused: blockIdx.x==64 (y==0) builds G=[W1;W2-W1] bf16-split + BB=b1+b2.
// ---------------------------------------------------------------------------
__global__ __launch_bounds__(256) void k_prep(const float* __restrict__ x,
                                              const float* __restrict__ W1,
                                              const float* __restrict__ b1,
                                              const float* __restrict__ W2,
                                              const float* __restrict__ b2,
                                              float* __restrict__ xt,
                                              __hip_bfloat16* __restrict__ xh,
                                              __hip_bfloat16* __restrict__ xl,
                                              float* __restrict__ sq,
                                              float* __restrict__ sqn,
                                              __hip_bfloat16* __restrict__ gh,
                                              __hip_bfloat16* __restrict__ gl,
                                              float* __restrict__ bb) {
  const int t = threadIdx.x;
  if (blockIdx.x == 64) {                       // fused gsplit (one block)
    if (blockIdx.y != 0) return;
#pragma unroll 1
    for (int i = t; i < 128 * 64; i += 256) {
      int o = i >> 6, c = i & 63;
      float g = (o < 64) ? W1[o * 64 + c]
                         : (W2[(o - 64) * 64 + c] - W1[(o - 64) * 64 + c]);
      __hip_bfloat16 h = __float2bfloat16(g);
      gh[i] = h;
      gl[i] = __float2bfloat16(g - __bfloat162float(h));
    }
    if (t < 64) bb[t] = b1[t] + b2[t];
    return;
  }
  __shared__ float tile[64][65];
  const int b  = blockIdx.y;
  const int n0 = blockIdx.x * 64;
#pragma unroll
  for (int i = 0; i < 16; ++i) {
    int lin = i * 256 + t;
    int c = lin >> 6, j = lin & 63;
    tile[j][c] = x[(size_t)b * 64 * NPTS + (size_t)c * NPTS + n0 + j];
  }
  __syncthreads();
#pragma unroll
  for (int i = 0; i < 16; ++i) {
    int lin = i * 256 + t;
    int j = lin >> 6, c = lin & 63;
    float v = tile[j][c];
    size_t o = ((size_t)b * NPTS + n0 + j) * 64 + c;
    xt[o] = v;
    __hip_bfloat16 h = __float2bfloat16(v);
    xh[o] = h;
    xl[o] = __float2bfloat16(v - __bfloat162float(h));
  }
  if (t < 64) {
    float s = 0.f;
#pragma unroll
    for (int c = 0; c < 64; ++c) { float v = tile[t][c]; s = fmaf(v, v, s); }
    sq [b * NPTS + t + n0] = s;
    sqn[b * NPTS + t + n0] = 0.5f * s;
  }
}

// ---------------------------------------------------------------------------
// B: barrier-free MFMA KNN (hh-only; exact rerank absorbs bf16 error).
// Rows negated once -> MFMA accumulates 0.5*dist >= 0; raw IEEE bits are the
// rank key. Chained K-half MFMAs (one accumulator per tile). Branchless
// insert into slot-major defer buffer (dummy slot 16), batch bitonic flush.
// launch_bounds(256,8): cap 64 VGPR -> 8 blocks/CU (LDS 17KB x 8 = 139KB).
// ---------------------------------------------------------------------------
struct Frag { bf16x8 h0, h1; f32x4 sv; };

__global__ __launch_bounds__(256, 8) void k_knn(const __hip_bfloat16* __restrict__ xh,
                                                const float* __restrict__ sqn,
                                                unsigned* __restrict__ part) {
  __shared__ unsigned bufu[17 * 256];             // 17 KB, slot-major (+dummy)

  const int tid  = threadIdx.x;
  const int w    = tid >> 6;                      // wave -> 16-row tile
  const int lane = tid & 63;
  const int quad = lane >> 4, l15 = lane & 15;
  const int rb   = blockIdx.x;                    // 0..63 row-block (64 rows)
  const int q    = blockIdx.y;                    // 0..3 col-quarter
  const int b    = blockIdx.z;                    // 0..7
  const size_t xbase = (size_t)b * NPTS * 64;
  const int c0   = q * 1024;
  const int nrow = rb * 64 + w * 16 + l15;        // this lane's row

  // persistent B-operand fragments: the wave's rows, sign-flipped (-x)
  const __hip_bfloat16* ph = xh + xbase + (size_t)nrow * 64 + quad * 8;
  bf16x8 rh0 = *(const bf16x8*)(ph);
  bf16x8 rh1 = *(const bf16x8*)(ph + 32);
  rh0 = rh0 ^ (short)0x8000;                      // bf16 negate = sign flip
  rh1 = rh1 ^ (short)0x8000;
  const float srh = sqn[b * NPTS + nrow];         // 0.5*sq of own row

  unsigned D[16];                                 // sorted ascending keys
#pragma unroll
  for (int i = 0; i < 16; ++i) D[i] = SENT;
  unsigned thr = SENT | 0xFFFu;
  int cnt = 0;

  auto ldfrag = [&](int t) -> Frag {
    Frag f;
    const __hip_bfloat16* ah = xh + xbase + (size_t)(c0 + t * 16 + l15) * 64 + quad * 8;
    f.h0 = *(const bf16x8*)(ah);
    f.h1 = *(const bf16x8*)(ah + 32);
    f.sv = *(const f32x4*)(sqn + b * NPTS + c0 + t * 16 + quad * 4);
    return f;
  };

  auto flush = [&]() {
    unsigned E[16];
#pragma unroll
    for (int j = 0; j < 16; ++j) E[j] = bufu[j * 256 + tid];   // conflict-free
#pragma unroll
    for (int j = 0; j < 16; ++j) E[j] = (j < cnt) ? E[j] : 0xFFFFFFFFu;
    // bitonic full sort ascending (n=16) -- proven network
#pragma unroll
    for (int k = 2; k <= 16; k <<= 1)
#pragma unroll
      for (int j = k >> 1; j > 0; j >>= 1)
#pragma unroll
        for (int i = 0; i < 16; ++i) {
          int l = i ^ j;
          if (l > i) {
            unsigned lo = min(E[i], E[l]), hi = max(E[i], E[l]);
            bool up = ((i & k) == 0);
            E[i] = up ? lo : hi;
            E[l] = up ? hi : lo;
          }
        }
    // keep 16 smallest of D (asc) ∪ E (asc): reverse-min + bitonic clean
    unsigned T[16];
#pragma unroll
    for (int i = 0; i < 16; ++i) T[i] = min(D[i], E[15 - i]);
#pragma unroll
    for (int j = 8; j > 0; j >>= 1)
#pragma unroll
      for (int i = 0; i < 16; ++i) {
        int l = i ^ j;
        if (l > i) {
          unsigned lo = min(T[i], T[l]);
          T[l] = max(T[i], T[l]);
          T[i] = lo;
        }
      }
#pragma unroll
    for (int i = 0; i < 16; ++i) D[i] = T[i];
    cnt = 0;
    thr = D[15] | 0xFFFu;
  };

  // branchless insert: key = hi-20 bits of float(0.5*dist) | cand index
  auto ins = [&](float s, int m) {
    unsigned u = __float_as_uint(s);              // monotone: s >= 0 always
    bool pass = (u <= thr);
    int slot = pass ? cnt : 16;                   // 16 = dummy slot
    bufu[slot * 256 + tid] = (u & 0xFFFFF000u) | (unsigned)m;
    cnt += pass;
  };

  // chained K-half MFMAs: one accumulator per tile (init = 0.5*sqc + 0.5*sqr)
  auto compute2 = [&](const Frag& fa, const Frag& fb, int tbase) {
    f32x4 m1 = fa.sv, m3 = fb.sv;
#pragma unroll
    for (int i = 0; i < 4; ++i) { m1[i] += srh; m3[i] += srh; }
    m1 = __builtin_amdgcn_mfma_f32_16x16x32_bf16(fa.h0, rh0, m1, 0, 0, 0);
    m3 = __builtin_amdgcn_mfma_f32_16x16x32_bf16(fb.h0, rh0, m3, 0, 0, 0);
    m1 = __builtin_amdgcn_mfma_f32_16x16x32_bf16(fa.h1, rh1, m1, 0, 0, 0);
    m3 = __builtin_amdgcn_mfma_f32_16x16x32_bf16(fb.h1, rh1, m3, 0, 0, 0);
    const int cb = c0 + tbase * 16 + quad * 4;
#pragma unroll
    for (int i = 0; i < 4; ++i) ins(m1[i], cb + i);
#pragma unroll
    for (int i = 0; i < 4; ++i) ins(m3[i], cb + 16 + i);
  };

  Frag a0 = ldfrag(0), a1 = ldfrag(1);
#pragma unroll 1
  for (int it = 0; it < 16; ++it) {
    const int t4 = it * 4;
    Frag b0 = ldfrag(t4 + 2), b1 = ldfrag(t4 + 3);
    compute2(a0, a1, t4);
    if (__any(cnt >= 9)) flush();                 // +8/block max -> never >16
    const int tn = (t4 + 4 < NT) ? t4 + 4 : 62;   // clamp: last prefetch dead
    a0 = ldfrag(tn);
    a1 = ldfrag(tn + 1);
    compute2(b0, b1, t4 + 2);
    if (__any(cnt >= 9)) flush();
  }
  flush();

  // cross-quad merge: 2 rounds of shfl_xor bitonic top-16 merging
#pragma unroll
  for (int rd = 0; rd < 2; ++rd) {
    const int dx = (rd == 0) ? 16 : 32;
    unsigned Bx[16], T[16];
#pragma unroll
    for (int i = 0; i < 16; ++i) Bx[i] = (unsigned)__shfl_xor((int)D[i], dx);
#pragma unroll
    for (int i = 0; i < 16; ++i) T[i] = min(D[i], Bx[15 - i]);
#pragma unroll
    for (int j = 8; j > 0; j >>= 1)
#pragma unroll
      for (int i = 0; i < 16; ++i) {
        int l = i ^ j;
        if (l > i) {
          unsigned lo = min(T[i], T[l]);
          T[l] = max(T[i], T[l]);
          T[i] = lo;
        }
      }
#pragma unroll
    for (int i = 0; i < 16; ++i) D[i] = T[i];
  }
  if (quad == 0) {
    const size_t base = (size_t)(b * NPTS + nrow) * PROW + (size_t)q * 16;
#pragma unroll
    for (int i = 0; i < 16; ++i) part[base + i] = D[i];
  }
}

// ---------------------------------------------------------------------------
// C+D fused: merge 64 partial keys -> top-20 (LDS handoff) -> exact fp32
// rerank -> knn[16]. 32-lane group per row, 8 rows per block. Keys are
// globally distinct (quarter-disjoint index bits) -> ranks unique, slots
// 0..19 exactly filled.
// ---------------------------------------------------------------------------
__global__ __launch_bounds__(256) void k_mr(const unsigned* __restrict__ part,
                                            const float* __restrict__ xt,
                                            const float* __restrict__ sq,
                                            int* __restrict__ knn) {
  __shared__ unsigned short lc[8][20];
  const int g   = threadIdx.x >> 5;               // group 0..7
  const int c   = threadIdx.x & 31;
  const int row = blockIdx.x * 8 + g;
  // phase 1: rank 64 keys with 32 lanes (2 keys/lane)
  const unsigned v0 = part[(size_t)row * PROW + c];
  const unsigned v1 = part[(size_t)row * PROW + 32 + c];
  int r0 = 0, r1 = 0;
#pragma unroll
  for (int j = 0; j < 32; ++j) {
    unsigned a = (unsigned)__shfl((int)v0, j, 32);
    unsigned d = (unsigned)__shfl((int)v1, j, 32);
    r0 += (a < v0) + (d < v0);
    r1 += (a < v1) + (d < v1);
  }
  if (r0 < 20) lc[g][r0] = (unsigned short)(v0 & 0xFFFu);
  if (r1 < 20) lc[g][r1] = (unsigned short)(v1 & 0xFFFu);
  __syncthreads();
  // phase 2: exact fp32 rerank of the 20 candidates (lanes 0..19 active)
  const int b = row >> 12;
  const int m = lc[g][c < 20 ? c : 0];
  const float4* cr = (const float4*)(xt + (size_t)row * 64);
  const float4* mr = (const float4*)(xt + ((size_t)(b << 12) + m) * 64);
  float d = 0.f;
#pragma unroll
  for (int j = 0; j < 16; ++j) {
    float4 a = cr[j], v = mr[j];
    d = fmaf(a.x, v.x, d); d = fmaf(a.y, v.y, d);
    d = fmaf(a.z, v.z, d); d = fmaf(a.w, v.w, d);
  }
  float key = sq[(b << 12) + m] - 2.f * d;          // exact fp32 rank key
  if (m == (row & 4095)) key = 1e30f;               // exclude self
  int rk = 0;
#pragma unroll
  for (int j = 0; j < 20; ++j) {
    float kj = __shfl(key, j, 32);
    int   mj = __shfl(m, j, 32);
    rk += (kj < key) || ((kj == key) && (mj < m));
  }
  if (c < 20 && rk < 16) knn[(size_t)row * 16 + rk] = m;
}

// ---------------------------------------------------------------------------
// E: MFMA P/Q GEMM. P = X·W1^T ; Q = X·(W2-W1)^T + (b1+b2), via G=[W1;W2-W1]
// bf16-split (hh+hl+lh). Wave = 16 rows x 128 outs (8 tiles, 48 MFMAs).
// ---------------------------------------------------------------------------
__global__ __launch_bounds__(256) void k_pq(const __hip_bfloat16* __restrict__ xh,
                                            const __hip_bfloat16* __restrict__ xl,
                                            const __hip_bfloat16* __restrict__ gh,
                                            const __hip_bfloat16* __restrict__ gl,
                                            const float* __restrict__ bb,
                                            float* __restrict__ P,
                                            float* __restrict__ Q) {
  const int tid  = threadIdx.x;
  const int w    = tid >> 6;
  const int lane = tid & 63;
  const int quad = lane >> 4, l15 = lane & 15;
  const int row0 = blockIdx.x * 64 + w * 16;

  const __hip_bfloat16* pa = xh + (size_t)(row0 + l15) * 64 + quad * 8;
  const __hip_bfloat16* pb = xl + (size_t)(row0 + l15) * 64 + quad * 8;
  const bf16x8 ah0 = *(const bf16x8*)(pa);
  const bf16x8 ah1 = *(const bf16x8*)(pa + 32);
  const bf16x8 al0 = *(const bf16x8*)(pb);
  const bf16x8 al1 = *(const bf16x8*)(pb + 32);

#pragma unroll
  for (int ct = 0; ct < 8; ++ct) {
    const __hip_bfloat16* qh = gh + (size_t)(ct * 16 + l15) * 64 + quad * 8;
    const __hip_bfloat16* ql = gl + (size_t)(ct * 16 + l15) * 64 + quad * 8;
    bf16x8 bh0 = *(const bf16x8*)(qh);
    bf16x8 bh1 = *(const bf16x8*)(qh + 32);
    bf16x8 bl0 = *(const bf16x8*)(ql);
    bf16x8 bl1 = *(const bf16x8*)(ql + 32);
    f32x4 m1 = { 0.f, 0.f, 0.f, 0.f };
    f32x4 m2 = m1, m3 = m1, m4 = m1, m5 = m1, m6 = m1;
    m1 = __builtin_amdgcn_mfma_f32_16x16x32_bf16(ah0, bh0, m1, 0, 0, 0);
    m2 = __builtin_amdgcn_mfma_f32_16x16x32_bf16(ah1, bh1, m2, 0, 0, 0);
    m3 = __builtin_amdgcn_mfma_f32_16x16x32_bf16(ah0, bl0, m3, 0, 0, 0);
    m4 = __builtin_amdgcn_mfma_f32_16x16x32_bf16(ah1, bl1, m4, 0, 0, 0);
    m5 = __builtin_amdgcn_mfma_f32_16x16x32_bf16(al0, bh0, m5, 0, 0, 0);
    m6 = __builtin_amdgcn_mfma_f32_16x16x32_bf16(al1, bh1, m6, 0, 0, 0);
    if (ct < 4) {
#pragma unroll
      for (int i = 0; i < 4; ++i) {
        float s = ((m1[i] + m2[i]) + (m3[i] + m4[i])) + (m5[i] + m6[i]);
        P[(size_t)(row0 + quad * 4 + i) * 64 + ct * 16 + l15] = s;
      }
    } else {
      const float bq = bb[(ct - 4) * 16 + l15];
#pragma unroll
      for (int i = 0; i < 4; ++i) {
        float s = ((m1[i] + m2[i]) + (m3[i] + m4[i])) + (m5[i] + m6[i]);
        Q[(size_t)(row0 + quad * 4 + i) * 64 + (ct - 4) * 16 + l15] = s + bq;
      }
    }
  }
}

// ---------------------------------------------------------------------------
// F: y[n][o] = relu(max_k (Q[n][o] + P[knn[n][k]][o]))
// ---------------------------------------------------------------------------
__global__ __launch_bounds__(256) void k_out(const float* __restrict__ P,
                                             const float* __restrict__ Q,
                                             const int* __restrict__ knn,
                                             float* __restrict__ out) {
  __shared__ float tile[64][65];
  const int b    = blockIdx.y;
  const int n0   = blockIdx.x * 64;
  const int wave = threadIdx.x >> 6;
  const int lane = threadIdx.x & 63;
  for (int i = 0; i < 16; ++i) {
    const int nl = wave * 16 + i;
    const int gn = b * NPTS + n0 + nl;
    float acc = -1e30f;
    const float qv = Q[(size_t)gn * 64 + lane];
    const int* id = knn + (size_t)gn * 16;
#pragma unroll
    for (int k = 0; k < 16; ++k) {
      int m = id[k];
      float p = P[((size_t)b * NPTS + m) * 64 + lane];
      acc = fmaxf(acc, qv + p);
    }
    tile[nl][lane] = fmaxf(acc, 0.f);
  }
  __syncthreads();
#pragma unroll
  for (int i = 0; i < 16; ++i) {
    const int o = i * 4 + wave;
    out[((size_t)b * 64 + o) * NPTS + n0 + lane] = tile[lane][o];
  }
}

// ---------------------------------------------------------------------------
extern "C" void kernel_launch(void* const* d_in, const int* in_sizes, int n_in,
                              void* d_out, int out_size, void* d_ws, size_t ws_size,
                              hipStream_t stream) {
  const float* x  = (const float*)d_in[0];
  const float* W1 = (const float*)d_in[1];
  const float* b1 = (const float*)d_in[2];
  const float* W2 = (const float*)d_in[3];
  const float* b2 = (const float*)d_in[4];
  float* out = (float*)d_out;

  // workspace ~27.6 MB
  float* ws = (float*)d_ws;
  const size_t NPT_ALL = (size_t)NB * NPTS;                 // 32768
  float*          XT   = ws;                                // 8.39 MB
  float*          SQ   = XT + NPT_ALL * 64;                 // 0.13 MB
  float*          SQN  = SQ + NPT_ALL;                      // 0.13 MB (0.5*sq)
  __hip_bfloat16* XH   = (__hip_bfloat16*)(SQN + NPT_ALL);  // 4.19 MB
  __hip_bfloat16* XL   = XH + NPT_ALL * 64;                 // 4.19 MB
  unsigned*       PART = (unsigned*)(XL + NPT_ALL * 64);    // 8.39 MB
  int*            KNN  = (int*)(PART + NPT_ALL * PROW);     // 2.10 MB
  __hip_bfloat16* GH   = (__hip_bfloat16*)(KNN + NPT_ALL * 16); // 16 KB
  __hip_bfloat16* GL   = GH + 128 * 64;                     // 16 KB
  float*          BB   = (float*)(GL + 128 * 64);           // 256 B
  float*          Pm   = (float*)PART;  // overlay: PART dead after k_mr
  float*          Qm   = XT;            // overlay: XT dead after k_mr (race-free)

  k_prep <<<dim3(NPTS / 64 + 1, NB), 256, 0, stream>>>(x, W1, b1, W2, b2,
                                                       XT, XH, XL, SQ, SQN,
                                                       GH, GL, BB);
  k_knn  <<<dim3(64, NQ, NB), 256, 0, stream>>>(XH, SQN, PART);
  k_mr   <<<dim3(NPT_ALL / 8), 256, 0, stream>>>(PART, XT, SQ, KNN);
  k_pq   <<<dim3(NPT_ALL / 64), 256, 0, stream>>>(XH, XL, GH, GL, BB, Pm, Qm);
  k_out  <<<dim3(NPTS / 64, NB), 256, 0, stream>>>(Pm, Qm, KNN, out);
}

// Round 3
// 314.271 us; speedup vs baseline: 1.6033x; 1.6033x over previous
//
#include <hip/hip_runtime.h>
#include <hip/hip_bf16.h>
#include <cstdint>

#define NB    8
#define NPTS  4096
#define NQ    4              // col-quarters (blockIdx.y)
#define NT    64             // cand tiles per quarter (1024/16)
#define PROW  64             // part row stride in u32 (4 quarters x 16)
#define SENT  0xFF000000u    // sentinel key (> any real positive-float key)

typedef __attribute__((ext_vector_type(8))) short bf16x8;
typedef __attribute__((ext_vector_type(4))) float f32x4;

// ---------------------------------------------------------------------------
// A: x [B,C,N] -> XT fp32 [B,N,64], XH/XL bf16 split, sq, sqn=0.5*sq.
// Fused: blockIdx.x==64 (y==0) builds G=[W1;W2-W1] bf16-split + BB=b1+b2.
// ---------------------------------------------------------------------------
__global__ __launch_bounds__(256) void k_prep(const float* __restrict__ x,
                                              const float* __restrict__ W1,
                                              const float* __restrict__ b1,
                                              const float* __restrict__ W2,
                                              const float* __restrict__ b2,
                                              float* __restrict__ xt,
                                              __hip_bfloat16* __restrict__ xh,
                                              __hip_bfloat16* __restrict__ xl,
                                              float* __restrict__ sq,
                                              float* __restrict__ sqn,
                                              __hip_bfloat16* __restrict__ gh,
                                              __hip_bfloat16* __restrict__ gl,
                                              float* __restrict__ bb) {
  const int t = threadIdx.x;
  if (blockIdx.x == 64) {                       // fused gsplit (one block)
    if (blockIdx.y != 0) return;
#pragma unroll 1
    for (int i = t; i < 128 * 64; i += 256) {
      int o = i >> 6, c = i & 63;
      float g = (o < 64) ? W1[o * 64 + c]
                         : (W2[(o - 64) * 64 + c] - W1[(o - 64) * 64 + c]);
      __hip_bfloat16 h = __float2bfloat16(g);
      gh[i] = h;
      gl[i] = __float2bfloat16(g - __bfloat162float(h));
    }
    if (t < 64) bb[t] = b1[t] + b2[t];
    return;
  }
  __shared__ float tile[64][65];
  const int b  = blockIdx.y;
  const int n0 = blockIdx.x * 64;
#pragma unroll
  for (int i = 0; i < 16; ++i) {
    int lin = i * 256 + t;
    int c = lin >> 6, j = lin & 63;
    tile[j][c] = x[(size_t)b * 64 * NPTS + (size_t)c * NPTS + n0 + j];
  }
  __syncthreads();
#pragma unroll
  for (int i = 0; i < 16; ++i) {
    int lin = i * 256 + t;
    int j = lin >> 6, c = lin & 63;
    float v = tile[j][c];
    size_t o = ((size_t)b * NPTS + n0 + j) * 64 + c;
    xt[o] = v;
    __hip_bfloat16 h = __float2bfloat16(v);
    xh[o] = h;
    xl[o] = __float2bfloat16(v - __bfloat162float(h));
  }
  if (t < 64) {
    float s = 0.f;
#pragma unroll
    for (int c = 0; c < 64; ++c) { float v = tile[t][c]; s = fmaf(v, v, s); }
    sq [b * NPTS + t + n0] = s;
    sqn[b * NPTS + t + n0] = 0.5f * s;
  }
}

// ---------------------------------------------------------------------------
// B: barrier-free MFMA KNN (hh-only; exact rerank absorbs bf16 error).
// Rows negated once -> MFMA accumulates 0.5*dist >= 0; raw IEEE bits are the
// rank key. Chained K-half MFMAs (one accumulator per tile). Branchless
// insert into slot-major defer buffer (dummy slot 16), batch bitonic flush.
// launch_bounds(256,4): 128-VGPR cap. (256,8) forced a 32-VGPR squeeze ->
// scratch spill (WRITE_SIZE 8MB -> 544MB, 3x slower). Do NOT raise the hint.
// ---------------------------------------------------------------------------
struct Frag { bf16x8 h0, h1; f32x4 sv; };

__global__ __launch_bounds__(256, 4) void k_knn(const __hip_bfloat16* __restrict__ xh,
                                                const float* __restrict__ sqn,
                                                unsigned* __restrict__ part) {
  __shared__ unsigned bufu[17 * 256];             // 17 KB, slot-major (+dummy)

  const int tid  = threadIdx.x;
  const int w    = tid >> 6;                      // wave -> 16-row tile
  const int lane = tid & 63;
  const int quad = lane >> 4, l15 = lane & 15;
  const int rb   = blockIdx.x;                    // 0..63 row-block (64 rows)
  const int q    = blockIdx.y;                    // 0..3 col-quarter
  const int b    = blockIdx.z;                    // 0..7
  const size_t xbase = (size_t)b * NPTS * 64;
  const int c0   = q * 1024;
  const int nrow = rb * 64 + w * 16 + l15;        // this lane's row

  // persistent B-operand fragments: the wave's rows, sign-flipped (-x)
  const __hip_bfloat16* ph = xh + xbase + (size_t)nrow * 64 + quad * 8;
  bf16x8 rh0 = *(const bf16x8*)(ph);
  bf16x8 rh1 = *(const bf16x8*)(ph + 32);
  rh0 = rh0 ^ (short)0x8000;                      // bf16 negate = sign flip
  rh1 = rh1 ^ (short)0x8000;
  const float srh = sqn[b * NPTS + nrow];         // 0.5*sq of own row

  unsigned D[16];                                 // sorted ascending keys
#pragma unroll
  for (int i = 0; i < 16; ++i) D[i] = SENT;
  unsigned thr = SENT | 0xFFFu;
  int cnt = 0;

  auto ldfrag = [&](int t) -> Frag {
    Frag f;
    const __hip_bfloat16* ah = xh + xbase + (size_t)(c0 + t * 16 + l15) * 64 + quad * 8;
    f.h0 = *(const bf16x8*)(ah);
    f.h1 = *(const bf16x8*)(ah + 32);
    f.sv = *(const f32x4*)(sqn + b * NPTS + c0 + t * 16 + quad * 4);
    return f;
  };

  auto flush = [&]() {
    unsigned E[16];
#pragma unroll
    for (int j = 0; j < 16; ++j) E[j] = bufu[j * 256 + tid];   // conflict-free
#pragma unroll
    for (int j = 0; j < 16; ++j) E[j] = (j < cnt) ? E[j] : 0xFFFFFFFFu;
    // bitonic full sort ascending (n=16) -- proven network
#pragma unroll
    for (int k = 2; k <= 16; k <<= 1)
#pragma unroll
      for (int j = k >> 1; j > 0; j >>= 1)
#pragma unroll
        for (int i = 0; i < 16; ++i) {
          int l = i ^ j;
          if (l > i) {
            unsigned lo = min(E[i], E[l]), hi = max(E[i], E[l]);
            bool up = ((i & k) == 0);
            E[i] = up ? lo : hi;
            E[l] = up ? hi : lo;
          }
        }
    // keep 16 smallest of D (asc) ∪ E (asc): reverse-min + bitonic clean
    unsigned T[16];
#pragma unroll
    for (int i = 0; i < 16; ++i) T[i] = min(D[i], E[15 - i]);
#pragma unroll
    for (int j = 8; j > 0; j >>= 1)
#pragma unroll
      for (int i = 0; i < 16; ++i) {
        int l = i ^ j;
        if (l > i) {
          unsigned lo = min(T[i], T[l]);
          T[l] = max(T[i], T[l]);
          T[i] = lo;
        }
      }
#pragma unroll
    for (int i = 0; i < 16; ++i) D[i] = T[i];
    cnt = 0;
    thr = D[15] | 0xFFFu;
  };

  // branchless insert: key = hi-20 bits of float(0.5*dist) | cand index
  auto ins = [&](float s, int m) {
    unsigned u = __float_as_uint(s);              // monotone: s >= 0 always
    bool pass = (u <= thr);
    int slot = pass ? cnt : 16;                   // 16 = dummy slot
    bufu[slot * 256 + tid] = (u & 0xFFFFF000u) | (unsigned)m;
    cnt += pass;
  };

  // chained K-half MFMAs: one accumulator per tile (init = 0.5*sqc + 0.5*sqr)
  auto compute2 = [&](const Frag& fa, const Frag& fb, int tbase) {
    f32x4 m1 = fa.sv, m3 = fb.sv;
#pragma unroll
    for (int i = 0; i < 4; ++i) { m1[i] += srh; m3[i] += srh; }
    m1 = __builtin_amdgcn_mfma_f32_16x16x32_bf16(fa.h0, rh0, m1, 0, 0, 0);
    m3 = __builtin_amdgcn_mfma_f32_16x16x32_bf16(fb.h0, rh0, m3, 0, 0, 0);
    m1 = __builtin_amdgcn_mfma_f32_16x16x32_bf16(fa.h1, rh1, m1, 0, 0, 0);
    m3 = __builtin_amdgcn_mfma_f32_16x16x32_bf16(fb.h1, rh1, m3, 0, 0, 0);
    const int cb = c0 + tbase * 16 + quad * 4;
#pragma unroll
    for (int i = 0; i < 4; ++i) ins(m1[i], cb + i);
#pragma unroll
    for (int i = 0; i < 4; ++i) ins(m3[i], cb + 16 + i);
  };

  Frag a0 = ldfrag(0), a1 = ldfrag(1);
#pragma unroll 1
  for (int it = 0; it < 16; ++it) {
    const int t4 = it * 4;
    Frag b0 = ldfrag(t4 + 2), b1 = ldfrag(t4 + 3);
    compute2(a0, a1, t4);
    if (__any(cnt >= 9)) flush();                 // +8/block max -> never >16
    const int tn = (t4 + 4 < NT) ? t4 + 4 : 62;   // clamp: last prefetch dead
    a0 = ldfrag(tn);
    a1 = ldfrag(tn + 1);
    compute2(b0, b1, t4 + 2);
    if (__any(cnt >= 9)) flush();
  }
  flush();

  // cross-quad merge: 2 rounds of shfl_xor bitonic top-16 merging
#pragma unroll
  for (int rd = 0; rd < 2; ++rd) {
    const int dx = (rd == 0) ? 16 : 32;
    unsigned Bx[16], T[16];
#pragma unroll
    for (int i = 0; i < 16; ++i) Bx[i] = (unsigned)__shfl_xor((int)D[i], dx);
#pragma unroll
    for (int i = 0; i < 16; ++i) T[i] = min(D[i], Bx[15 - i]);
#pragma unroll
    for (int j = 8; j > 0; j >>= 1)
#pragma unroll
      for (int i = 0; i < 16; ++i) {
        int l = i ^ j;
        if (l > i) {
          unsigned lo = min(T[i], T[l]);
          T[l] = max(T[i], T[l]);
          T[i] = lo;
        }
      }
#pragma unroll
    for (int i = 0; i < 16; ++i) D[i] = T[i];
  }
  if (quad == 0) {
    const size_t base = (size_t)(b * NPTS + nrow) * PROW + (size_t)q * 16;
#pragma unroll
    for (int i = 0; i < 16; ++i) part[base + i] = D[i];
  }
}

// ---------------------------------------------------------------------------
// C+D fused: merge 64 partial keys -> top-20 (LDS handoff) -> exact fp32
// rerank -> knn[16]. 32-lane group per row, 8 rows per block. Keys are
// globally distinct (quarter-disjoint index bits) -> ranks unique, slots
// 0..19 exactly filled.
// ---------------------------------------------------------------------------
__global__ __launch_bounds__(256) void k_mr(const unsigned* __restrict__ part,
                                            const float* __restrict__ xt,
                                            const float* __restrict__ sq,
                                            int* __restrict__ knn) {
  __shared__ unsigned short lc[8][20];
  const int g   = threadIdx.x >> 5;               // group 0..7
  const int c   = threadIdx.x & 31;
  const int row = blockIdx.x * 8 + g;
  // phase 1: rank 64 keys with 32 lanes (2 keys/lane)
  const unsigned v0 = part[(size_t)row * PROW + c];
  const unsigned v1 = part[(size_t)row * PROW + 32 + c];
  int r0 = 0, r1 = 0;
#pragma unroll
  for (int j = 0; j < 32; ++j) {
    unsigned a = (unsigned)__shfl((int)v0, j, 32);
    unsigned d = (unsigned)__shfl((int)v1, j, 32);
    r0 += (a < v0) + (d < v0);
    r1 += (a < v1) + (d < v1);
  }
  if (r0 < 20) lc[g][r0] = (unsigned short)(v0 & 0xFFFu);
  if (r1 < 20) lc[g][r1] = (unsigned short)(v1 & 0xFFFu);
  __syncthreads();
  // phase 2: exact fp32 rerank of the 20 candidates (lanes 0..19 active)
  const int b = row >> 12;
  const int m = lc[g][c < 20 ? c : 0];
  const float4* cr = (const float4*)(xt + (size_t)row * 64);
  const float4* mr = (const float4*)(xt + ((size_t)(b << 12) + m) * 64);
  float d = 0.f;
#pragma unroll
  for (int j = 0; j < 16; ++j) {
    float4 a = cr[j], v = mr[j];
    d = fmaf(a.x, v.x, d); d = fmaf(a.y, v.y, d);
    d = fmaf(a.z, v.z, d); d = fmaf(a.w, v.w, d);
  }
  float key = sq[(b << 12) + m] - 2.f * d;          // exact fp32 rank key
  if (m == (row & 4095)) key = 1e30f;               // exclude self
  int rk = 0;
#pragma unroll
  for (int j = 0; j < 20; ++j) {
    float kj = __shfl(key, j, 32);
    int   mj = __shfl(m, j, 32);
    rk += (kj < key) || ((kj == key) && (mj < m));
  }
  if (c < 20 && rk < 16) knn[(size_t)row * 16 + rk] = m;
}

// ---------------------------------------------------------------------------
// E: MFMA P/Q GEMM. P = X·W1^T ; Q = X·(W2-W1)^T + (b1+b2), via G=[W1;W2-W1]
// bf16-split (hh+hl+lh). Wave = 16 rows x 128 outs (8 tiles, 48 MFMAs).
// ---------------------------------------------------------------------------
__global__ __launch_bounds__(256) void k_pq(const __hip_bfloat16* __restrict__ xh,
                                            const __hip_bfloat16* __restrict__ xl,
                                            const __hip_bfloat16* __restrict__ gh,
                                            const __hip_bfloat16* __restrict__ gl,
                                            const float* __restrict__ bb,
                                            float* __restrict__ P,
                                            float* __restrict__ Q) {
  const int tid  = threadIdx.x;
  const int w    = tid >> 6;
  const int lane = tid & 63;
  const int quad = lane >> 4, l15 = lane & 15;
  const int row0 = blockIdx.x * 64 + w * 16;

  const __hip_bfloat16* pa = xh + (size_t)(row0 + l15) * 64 + quad * 8;
  const __hip_bfloat16* pb = xl + (size_t)(row0 + l15) * 64 + quad * 8;
  const bf16x8 ah0 = *(const bf16x8*)(pa);
  const bf16x8 ah1 = *(const bf16x8*)(pa + 32);
  const bf16x8 al0 = *(const bf16x8*)(pb);
  const bf16x8 al1 = *(const bf16x8*)(pb + 32);

#pragma unroll
  for (int ct = 0; ct < 8; ++ct) {
    const __hip_bfloat16* qh = gh + (size_t)(ct * 16 + l15) * 64 + quad * 8;
    const __hip_bfloat16* ql = gl + (size_t)(ct * 16 + l15) * 64 + quad * 8;
    bf16x8 bh0 = *(const bf16x8*)(qh);
    bf16x8 bh1 = *(const bf16x8*)(qh + 32);
    bf16x8 bl0 = *(const bf16x8*)(ql);
    bf16x8 bl1 = *(const bf16x8*)(ql + 32);
    f32x4 m1 = { 0.f, 0.f, 0.f, 0.f };
    f32x4 m2 = m1, m3 = m1, m4 = m1, m5 = m1, m6 = m1;
    m1 = __builtin_amdgcn_mfma_f32_16x16x32_bf16(ah0, bh0, m1, 0, 0, 0);
    m2 = __builtin_amdgcn_mfma_f32_16x16x32_bf16(ah1, bh1, m2, 0, 0, 0);
    m3 = __builtin_amdgcn_mfma_f32_16x16x32_bf16(ah0, bl0, m3, 0, 0, 0);
    m4 = __builtin_amdgcn_mfma_f32_16x16x32_bf16(ah1, bl1, m4, 0, 0, 0);
    m5 = __builtin_amdgcn_mfma_f32_16x16x32_bf16(al0, bh0, m5, 0, 0, 0);
    m6 = __builtin_amdgcn_mfma_f32_16x16x32_bf16(al1, bh1, m6, 0, 0, 0);
    if (ct < 4) {
#pragma unroll
      for (int i = 0; i < 4; ++i) {
        float s = ((m1[i] + m2[i]) + (m3[i] + m4[i])) + (m5[i] + m6[i]);
        P[(size_t)(row0 + quad * 4 + i) * 64 + ct * 16 + l15] = s;
      }
    } else {
      const float bq = bb[(ct - 4) * 16 + l15];
#pragma unroll
      for (int i = 0; i < 4; ++i) {
        float s = ((m1[i] + m2[i]) + (m3[i] + m4[i])) + (m5[i] + m6[i]);
        Q[(size_t)(row0 + quad * 4 + i) * 64 + (ct - 4) * 16 + l15] = s + bq;
      }
    }
  }
}

// ---------------------------------------------------------------------------
// F: y[n][o] = relu(max_k (Q[n][o] + P[knn[n][k]][o]))
// ---------------------------------------------------------------------------
__global__ __launch_bounds__(256) void k_out(const float* __restrict__ P,
                                             const float* __restrict__ Q,
                                             const int* __restrict__ knn,
                                             float* __restrict__ out) {
  __shared__ float tile[64][65];
  const int b    = blockIdx.y;
  const int n0   = blockIdx.x * 64;
  const int wave = threadIdx.x >> 6;
  const int lane = threadIdx.x & 63;
  for (int i = 0; i < 16; ++i) {
    const int nl = wave * 16 + i;
    const int gn = b * NPTS + n0 + nl;
    float acc = -1e30f;
    const float qv = Q[(size_t)gn * 64 + lane];
    const int* id = knn + (size_t)gn * 16;
#pragma unroll
    for (int k = 0; k < 16; ++k) {
      int m = id[k];
      float p = P[((size_t)b * NPTS + m) * 64 + lane];
      acc = fmaxf(acc, qv + p);
    }
    tile[nl][lane] = fmaxf(acc, 0.f);
  }
  __syncthreads();
#pragma unroll
  for (int i = 0; i < 16; ++i) {
    const int o = i * 4 + wave;
    out[((size_t)b * 64 + o) * NPTS + n0 + lane] = tile[lane][o];
  }
}

// ---------------------------------------------------------------------------
extern "C" void kernel_launch(void* const* d_in, const int* in_sizes, int n_in,
                              void* d_out, int out_size, void* d_ws, size_t ws_size,
                              hipStream_t stream) {
  const float* x  = (const float*)d_in[0];
  const float* W1 = (const float*)d_in[1];
  const float* b1 = (const float*)d_in[2];
  const float* W2 = (const float*)d_in[3];
  const float* b2 = (const float*)d_in[4];
  float* out = (float*)d_out;

  // workspace ~27.6 MB
  float* ws = (float*)d_ws;
  const size_t NPT_ALL = (size_t)NB * NPTS;                 // 32768
  float*          XT   = ws;                                // 8.39 MB
  float*          SQ   = XT + NPT_ALL * 64;                 // 0.13 MB
  float*          SQN  = SQ + NPT_ALL;                      // 0.13 MB (0.5*sq)
  __hip_bfloat16* XH   = (__hip_bfloat16*)(SQN + NPT_ALL);  // 4.19 MB
  __hip_bfloat16* XL   = XH + NPT_ALL * 64;                 // 4.19 MB
  unsigned*       PART = (unsigned*)(XL + NPT_ALL * 64);    // 8.39 MB
  int*            KNN  = (int*)(PART + NPT_ALL * PROW);     // 2.10 MB
  __hip_bfloat16* GH   = (__hip_bfloat16*)(KNN + NPT_ALL * 16); // 16 KB
  __hip_bfloat16* GL   = GH + 128 * 64;                     // 16 KB
  float*          BB   = (float*)(GL + 128 * 64);           // 256 B
  float*          Pm   = (float*)PART;  // overlay: PART dead after k_mr
  float*          Qm   = XT;            // overlay: XT dead after k_mr (race-free)

  k_prep <<<dim3(NPTS / 64 + 1, NB), 256, 0, stream>>>(x, W1, b1, W2, b2,
                                                       XT, XH, XL, SQ, SQN,
                                                       GH, GL, BB);
  k_knn  <<<dim3(64, NQ, NB), 256, 0, stream>>>(XH, SQN, PART);
  k_mr   <<<dim3(NPT_ALL / 8), 256, 0, stream>>>(PART, XT, SQ, KNN);
  k_pq   <<<dim3(NPT_ALL / 64), 256, 0, stream>>>(XH, XL, GH, GL, BB, Pm, Qm);
  k_out  <<<dim3(NPTS / 64, NB), 256, 0, stream>>>(Pm, Qm, KNN, out);
}

// Round 4
// 296.010 us; speedup vs baseline: 1.7022x; 1.0617x over previous
//
#include <hip/hip_runtime.h>
#include <hip/hip_bf16.h>
#include <cstdint>

#define NB    8
#define NPTS  4096
#define NQ    4              // col-quarters (blockIdx.y)
#define NT    64             // cand tiles per quarter (1024/16)
#define PROW  64             // part row stride in u32 (4 quarters x 16)
#define SENT  0xFF000000u    // sentinel key (> any real positive-float key)
#define KNN_T 512            // k_knn block size (8 waves) -- occupancy probe

typedef __attribute__((ext_vector_type(8))) short bf16x8;
typedef __attribute__((ext_vector_type(4))) float f32x4;

// ---------------------------------------------------------------------------
// A: x [B,C,N] -> XT fp32 [B,N,64], XH/XL bf16 split, sq, sqn=0.5*sq.
// Fused: blockIdx.x==64 (y==0) builds G=[W1;W2-W1] bf16-split + BB=b1+b2.
// ---------------------------------------------------------------------------
__global__ __launch_bounds__(256) void k_prep(const float* __restrict__ x,
                                              const float* __restrict__ W1,
                                              const float* __restrict__ b1,
                                              const float* __restrict__ W2,
                                              const float* __restrict__ b2,
                                              float* __restrict__ xt,
                                              __hip_bfloat16* __restrict__ xh,
                                              __hip_bfloat16* __restrict__ xl,
                                              float* __restrict__ sq,
                                              float* __restrict__ sqn,
                                              __hip_bfloat16* __restrict__ gh,
                                              __hip_bfloat16* __restrict__ gl,
                                              float* __restrict__ bb) {
  const int t = threadIdx.x;
  if (blockIdx.x == 64) {                       // fused gsplit (one block)
    if (blockIdx.y != 0) return;
#pragma unroll 1
    for (int i = t; i < 128 * 64; i += 256) {
      int o = i >> 6, c = i & 63;
      float g = (o < 64) ? W1[o * 64 + c]
                         : (W2[(o - 64) * 64 + c] - W1[(o - 64) * 64 + c]);
      __hip_bfloat16 h = __float2bfloat16(g);
      gh[i] = h;
      gl[i] = __float2bfloat16(g - __bfloat162float(h));
    }
    if (t < 64) bb[t] = b1[t] + b2[t];
    return;
  }
  __shared__ float tile[64][65];
  const int b  = blockIdx.y;
  const int n0 = blockIdx.x * 64;
#pragma unroll
  for (int i = 0; i < 16; ++i) {
    int lin = i * 256 + t;
    int c = lin >> 6, j = lin & 63;
    tile[j][c] = x[(size_t)b * 64 * NPTS + (size_t)c * NPTS + n0 + j];
  }
  __syncthreads();
#pragma unroll
  for (int i = 0; i < 16; ++i) {
    int lin = i * 256 + t;
    int j = lin >> 6, c = lin & 63;
    float v = tile[j][c];
    size_t o = ((size_t)b * NPTS + n0 + j) * 64 + c;
    xt[o] = v;
    __hip_bfloat16 h = __float2bfloat16(v);
    xh[o] = h;
    xl[o] = __float2bfloat16(v - __bfloat162float(h));
  }
  if (t < 64) {
    float s = 0.f;
#pragma unroll
    for (int c = 0; c < 64; ++c) { float v = tile[t][c]; s = fmaf(v, v, s); }
    sq [b * NPTS + t + n0] = s;
    sqn[b * NPTS + t + n0] = 0.5f * s;
  }
}

// ---------------------------------------------------------------------------
// B: barrier-free MFMA KNN (hh-only; exact rerank absorbs bf16 error).
// Rows negated once -> MFMA accumulates 0.5*dist >= 0; raw IEEE bits are the
// rank key. Chained K-half MFMAs. Branchless insert into slot-major defer
// buffer (dummy slot 16), batch bitonic flush.
// OCCUPANCY PROBE: 512-thread blocks (8 waves, 128 rows), grid 1024 -> if a
// per-CU workgroup cap (~4) was limiting residency, waves/CU goes 13->32.
// Per-thread code identical; wave-scoped ops only, no barriers.
// launch_bounds(512,4): 128-VGPR cap. DO NOT demand more waves/EU: (256,8)
// forced a 32-VGPR squeeze -> scratch spill (WRITE 8MB->544MB, 3x slower).
// ---------------------------------------------------------------------------
struct Frag { bf16x8 h0, h1; f32x4 sv; };

__global__ __launch_bounds__(KNN_T, 4) void k_knn(const __hip_bfloat16* __restrict__ xh,
                                                  const float* __restrict__ sqn,
                                                  unsigned* __restrict__ part) {
  __shared__ unsigned bufu[17 * KNN_T];           // 34 KB, slot-major (+dummy)

  const int tid  = threadIdx.x;
  const int w    = tid >> 6;                      // wave -> 16-row tile
  const int lane = tid & 63;
  const int quad = lane >> 4, l15 = lane & 15;
  const int rb   = blockIdx.x;                    // 0..31 row-block (128 rows)
  const int q    = blockIdx.y;                    // 0..3 col-quarter
  const int b    = blockIdx.z;                    // 0..7
  const size_t xbase = (size_t)b * NPTS * 64;
  const int c0   = q * 1024;
  const int nrow = rb * (KNN_T / 4) + w * 16 + l15;  // this lane's row

  // persistent B-operand fragments: the wave's rows, sign-flipped (-x)
  const __hip_bfloat16* ph = xh + xbase + (size_t)nrow * 64 + quad * 8;
  bf16x8 rh0 = *(const bf16x8*)(ph);
  bf16x8 rh1 = *(const bf16x8*)(ph + 32);
  rh0 = rh0 ^ (short)0x8000;                      // bf16 negate = sign flip
  rh1 = rh1 ^ (short)0x8000;
  const float srh = sqn[b * NPTS + nrow];         // 0.5*sq of own row

  unsigned D[16];                                 // sorted ascending keys
#pragma unroll
  for (int i = 0; i < 16; ++i) D[i] = SENT;
  unsigned thr = SENT | 0xFFFu;
  int cnt = 0;

  auto ldfrag = [&](int t) -> Frag {
    Frag f;
    const __hip_bfloat16* ah = xh + xbase + (size_t)(c0 + t * 16 + l15) * 64 + quad * 8;
    f.h0 = *(const bf16x8*)(ah);
    f.h1 = *(const bf16x8*)(ah + 32);
    f.sv = *(const f32x4*)(sqn + b * NPTS + c0 + t * 16 + quad * 4);
    return f;
  };

  auto flush = [&]() {
    unsigned E[16];
#pragma unroll
    for (int j = 0; j < 16; ++j) E[j] = bufu[j * KNN_T + tid];  // conflict-free
#pragma unroll
    for (int j = 0; j < 16; ++j) E[j] = (j < cnt) ? E[j] : 0xFFFFFFFFu;
    // bitonic full sort ascending (n=16) -- proven network
#pragma unroll
    for (int k = 2; k <= 16; k <<= 1)
#pragma unroll
      for (int j = k >> 1; j > 0; j >>= 1)
#pragma unroll
        for (int i = 0; i < 16; ++i) {
          int l = i ^ j;
          if (l > i) {
            unsigned lo = min(E[i], E[l]), hi = max(E[i], E[l]);
            bool up = ((i & k) == 0);
            E[i] = up ? lo : hi;
            E[l] = up ? hi : lo;
          }
        }
    // keep 16 smallest of D (asc) ∪ E (asc): reverse-min + bitonic clean
    unsigned T[16];
#pragma unroll
    for (int i = 0; i < 16; ++i) T[i] = min(D[i], E[15 - i]);
#pragma unroll
    for (int j = 8; j > 0; j >>= 1)
#pragma unroll
      for (int i = 0; i < 16; ++i) {
        int l = i ^ j;
        if (l > i) {
          unsigned lo = min(T[i], T[l]);
          T[l] = max(T[i], T[l]);
          T[i] = lo;
        }
      }
#pragma unroll
    for (int i = 0; i < 16; ++i) D[i] = T[i];
    cnt = 0;
    thr = D[15] | 0xFFFu;
  };

  // branchless insert: key = hi-20 bits of float(0.5*dist) | cand index
  auto ins = [&](float s, int m) {
    unsigned u = __float_as_uint(s);              // monotone: s >= 0 always
    bool pass = (u <= thr);
    int slot = pass ? cnt : 16;                   // 16 = dummy slot
    bufu[slot * KNN_T + tid] = (u & 0xFFFFF000u) | (unsigned)m;
    cnt += pass;
  };

  // chained K-half MFMAs: one accumulator per tile (init = 0.5*sqc + 0.5*sqr)
  auto compute2 = [&](const Frag& fa, const Frag& fb, int tbase) {
    f32x4 m1 = fa.sv, m3 = fb.sv;
#pragma unroll
    for (int i = 0; i < 4; ++i) { m1[i] += srh; m3[i] += srh; }
    m1 = __builtin_amdgcn_mfma_f32_16x16x32_bf16(fa.h0, rh0, m1, 0, 0, 0);
    m3 = __builtin_amdgcn_mfma_f32_16x16x32_bf16(fb.h0, rh0, m3, 0, 0, 0);
    m1 = __builtin_amdgcn_mfma_f32_16x16x32_bf16(fa.h1, rh1, m1, 0, 0, 0);
    m3 = __builtin_amdgcn_mfma_f32_16x16x32_bf16(fb.h1, rh1, m3, 0, 0, 0);
    const int cb = c0 + tbase * 16 + quad * 4;
#pragma unroll
    for (int i = 0; i < 4; ++i) ins(m1[i], cb + i);
#pragma unroll
    for (int i = 0; i < 4; ++i) ins(m3[i], cb + 16 + i);
  };

  Frag a0 = ldfrag(0), a1 = ldfrag(1);
#pragma unroll 1
  for (int it = 0; it < 16; ++it) {
    const int t4 = it * 4;
    Frag b0 = ldfrag(t4 + 2), b1 = ldfrag(t4 + 3);
    compute2(a0, a1, t4);
    if (__any(cnt >= 9)) flush();                 // +8/block max -> never >16
    const int tn = (t4 + 4 < NT) ? t4 + 4 : 62;   // clamp: last prefetch dead
    a0 = ldfrag(tn);
    a1 = ldfrag(tn + 1);
    compute2(b0, b1, t4 + 2);
    if (__any(cnt >= 9)) flush();
  }
  flush();

  // cross-quad merge: 2 rounds of shfl_xor bitonic top-16 merging
#pragma unroll
  for (int rd = 0; rd < 2; ++rd) {
    const int dx = (rd == 0) ? 16 : 32;
    unsigned Bx[16], T[16];
#pragma unroll
    for (int i = 0; i < 16; ++i) Bx[i] = (unsigned)__shfl_xor((int)D[i], dx);
#pragma unroll
    for (int i = 0; i < 16; ++i) T[i] = min(D[i], Bx[15 - i]);
#pragma unroll
    for (int j = 8; j > 0; j >>= 1)
#pragma unroll
      for (int i = 0; i < 16; ++i) {
        int l = i ^ j;
        if (l > i) {
          unsigned lo = min(T[i], T[l]);
          T[l] = max(T[i], T[l]);
          T[i] = lo;
        }
      }
#pragma unroll
    for (int i = 0; i < 16; ++i) D[i] = T[i];
  }
  if (quad == 0) {
    const size_t base = (size_t)(b * NPTS + nrow) * PROW + (size_t)q * 16;
#pragma unroll
    for (int i = 0; i < 16; ++i) part[base + i] = D[i];
  }
}

// ---------------------------------------------------------------------------
// C+D fused: merge 64 partial keys -> top-20 (LDS handoff) -> exact fp32
// rerank -> knn[16]. 32-lane group per row, 8 rows per block. Keys are
// globally distinct (quarter-disjoint index bits) -> ranks unique, slots
// 0..19 exactly filled.
// ---------------------------------------------------------------------------
__global__ __launch_bounds__(256) void k_mr(const unsigned* __restrict__ part,
                                            const float* __restrict__ xt,
                                            const float* __restrict__ sq,
                                            int* __restrict__ knn) {
  __shared__ unsigned short lc[8][20];
  const int g   = threadIdx.x >> 5;               // group 0..7
  const int c   = threadIdx.x & 31;
  const int row = blockIdx.x * 8 + g;
  // phase 1: rank 64 keys with 32 lanes (2 keys/lane)
  const unsigned v0 = part[(size_t)row * PROW + c];
  const unsigned v1 = part[(size_t)row * PROW + 32 + c];
  int r0 = 0, r1 = 0;
#pragma unroll
  for (int j = 0; j < 32; ++j) {
    unsigned a = (unsigned)__shfl((int)v0, j, 32);
    unsigned d = (unsigned)__shfl((int)v1, j, 32);
    r0 += (a < v0) + (d < v0);
    r1 += (a < v1) + (d < v1);
  }
  if (r0 < 20) lc[g][r0] = (unsigned short)(v0 & 0xFFFu);
  if (r1 < 20) lc[g][r1] = (unsigned short)(v1 & 0xFFFu);
  __syncthreads();
  // phase 2: exact fp32 rerank of the 20 candidates (lanes 0..19 active)
  const int b = row >> 12;
  const int m = lc[g][c < 20 ? c : 0];
  const float4* cr = (const float4*)(xt + (size_t)row * 64);
  const float4* mr = (const float4*)(xt + ((size_t)(b << 12) + m) * 64);
  float d = 0.f;
#pragma unroll
  for (int j = 0; j < 16; ++j) {
    float4 a = cr[j], v = mr[j];
    d = fmaf(a.x, v.x, d); d = fmaf(a.y, v.y, d);
    d = fmaf(a.z, v.z, d); d = fmaf(a.w, v.w, d);
  }
  float key = sq[(b << 12) + m] - 2.f * d;          // exact fp32 rank key
  if (m == (row & 4095)) key = 1e30f;               // exclude self
  int rk = 0;
#pragma unroll
  for (int j = 0; j < 20; ++j) {
    float kj = __shfl(key, j, 32);
    int   mj = __shfl(m, j, 32);
    rk += (kj < key) || ((kj == key) && (mj < m));
  }
  if (c < 20 && rk < 16) knn[(size_t)row * 16 + rk] = m;
}

// ---------------------------------------------------------------------------
// E: MFMA P/Q GEMM. P = X·W1^T ; Q = X·(W2-W1)^T + (b1+b2), via G=[W1;W2-W1]
// bf16-split (hh+hl+lh). Wave = 16 rows x 128 outs (8 tiles, 48 MFMAs).
// ---------------------------------------------------------------------------
__global__ __launch_bounds__(256) void k_pq(const __hip_bfloat16* __restrict__ xh,
                                            const __hip_bfloat16* __restrict__ xl,
                                            const __hip_bfloat16* __restrict__ gh,
                                            const __hip_bfloat16* __restrict__ gl,
                                            const float* __restrict__ bb,
                                            float* __restrict__ P,
                                            float* __restrict__ Q) {
  const int tid  = threadIdx.x;
  const int w    = tid >> 6;
  const int lane = tid & 63;
  const int quad = lane >> 4, l15 = lane & 15;
  const int row0 = blockIdx.x * 64 + w * 16;

  const __hip_bfloat16* pa = xh + (size_t)(row0 + l15) * 64 + quad * 8;
  const __hip_bfloat16* pb = xl + (size_t)(row0 + l15) * 64 + quad * 8;
  const bf16x8 ah0 = *(const bf16x8*)(pa);
  const bf16x8 ah1 = *(const bf16x8*)(pa + 32);
  const bf16x8 al0 = *(const bf16x8*)(pb);
  const bf16x8 al1 = *(const bf16x8*)(pb + 32);

#pragma unroll
  for (int ct = 0; ct < 8; ++ct) {
    const __hip_bfloat16* qh = gh + (size_t)(ct * 16 + l15) * 64 + quad * 8;
    const __hip_bfloat16* ql = gl + (size_t)(ct * 16 + l15) * 64 + quad * 8;
    bf16x8 bh0 = *(const bf16x8*)(qh);
    bf16x8 bh1 = *(const bf16x8*)(qh + 32);
    bf16x8 bl0 = *(const bf16x8*)(ql);
    bf16x8 bl1 = *(const bf16x8*)(ql + 32);
    f32x4 m1 = { 0.f, 0.f, 0.f, 0.f };
    f32x4 m2 = m1, m3 = m1, m4 = m1, m5 = m1, m6 = m1;
    m1 = __builtin_amdgcn_mfma_f32_16x16x32_bf16(ah0, bh0, m1, 0, 0, 0);
    m2 = __builtin_amdgcn_mfma_f32_16x16x32_bf16(ah1, bh1, m2, 0, 0, 0);
    m3 = __builtin_amdgcn_mfma_f32_16x16x32_bf16(ah0, bl0, m3, 0, 0, 0);
    m4 = __builtin_amdgcn_mfma_f32_16x16x32_bf16(ah1, bl1, m4, 0, 0, 0);
    m5 = __builtin_amdgcn_mfma_f32_16x16x32_bf16(al0, bh0, m5, 0, 0, 0);
    m6 = __builtin_amdgcn_mfma_f32_16x16x32_bf16(al1, bh1, m6, 0, 0, 0);
    if (ct < 4) {
#pragma unroll
      for (int i = 0; i < 4; ++i) {
        float s = ((m1[i] + m2[i]) + (m3[i] + m4[i])) + (m5[i] + m6[i]);
        P[(size_t)(row0 + quad * 4 + i) * 64 + ct * 16 + l15] = s;
      }
    } else {
      const float bq = bb[(ct - 4) * 16 + l15];
#pragma unroll
      for (int i = 0; i < 4; ++i) {
        float s = ((m1[i] + m2[i]) + (m3[i] + m4[i])) + (m5[i] + m6[i]);
        Q[(size_t)(row0 + quad * 4 + i) * 64 + (ct - 4) * 16 + l15] = s + bq;
      }
    }
  }
}

// ---------------------------------------------------------------------------
// F: y[n][o] = relu(max_k (Q[n][o] + P[knn[n][k]][o]))
// 512 threads (8 waves x 8 rows) -> 16 waves/CU at grid 512 (was 8).
// ---------------------------------------------------------------------------
__global__ __launch_bounds__(512) void k_out(const float* __restrict__ P,
                                             const float* __restrict__ Q,
                                             const int* __restrict__ knn,
                                             float* __restrict__ out) {
  __shared__ float tile[64][65];
  const int b    = blockIdx.y;
  const int n0   = blockIdx.x * 64;
  const int wave = threadIdx.x >> 6;              // 0..7
  const int lane = threadIdx.x & 63;
#pragma unroll 1
  for (int i = 0; i < 8; ++i) {
    const int nl = wave * 8 + i;
    const int gn = b * NPTS + n0 + nl;
    float acc = -1e30f;
    const float qv = Q[(size_t)gn * 64 + lane];
    const int* id = knn + (size_t)gn * 16;
#pragma unroll
    for (int k = 0; k < 16; ++k) {
      int m = id[k];
      float p = P[((size_t)b * NPTS + m) * 64 + lane];
      acc = fmaxf(acc, qv + p);
    }
    tile[nl][lane] = fmaxf(acc, 0.f);
  }
  __syncthreads();
#pragma unroll
  for (int i = 0; i < 8; ++i) {
    const int o = i * 8 + wave;
    out[((size_t)b * 64 + o) * NPTS + n0 + lane] = tile[lane][o];
  }
}

// ---------------------------------------------------------------------------
extern "C" void kernel_launch(void* const* d_in, const int* in_sizes, int n_in,
                              void* d_out, int out_size, void* d_ws, size_t ws_size,
                              hipStream_t stream) {
  const float* x  = (const float*)d_in[0];
  const float* W1 = (const float*)d_in[1];
  const float* b1 = (const float*)d_in[2];
  const float* W2 = (const float*)d_in[3];
  const float* b2 = (const float*)d_in[4];
  float* out = (float*)d_out;

  // workspace ~27.6 MB
  float* ws = (float*)d_ws;
  const size_t NPT_ALL = (size_t)NB * NPTS;                 // 32768
  float*          XT   = ws;                                // 8.39 MB
  float*          SQ   = XT + NPT_ALL * 64;                 // 0.13 MB
  float*          SQN  = SQ + NPT_ALL;                      // 0.13 MB (0.5*sq)
  __hip_bfloat16* XH   = (__hip_bfloat16*)(SQN + NPT_ALL);  // 4.19 MB
  __hip_bfloat16* XL   = XH + NPT_ALL * 64;                 // 4.19 MB
  unsigned*       PART = (unsigned*)(XL + NPT_ALL * 64);    // 8.39 MB
  int*            KNN  = (int*)(PART + NPT_ALL * PROW);     // 2.10 MB
  __hip_bfloat16* GH   = (__hip_bfloat16*)(KNN + NPT_ALL * 16); // 16 KB
  __hip_bfloat16* GL   = GH + 128 * 64;                     // 16 KB
  float*          BB   = (float*)(GL + 128 * 64);           // 256 B
  float*          Pm   = (float*)PART;  // overlay: PART dead after k_mr
  float*          Qm   = XT;            // overlay: XT dead after k_mr (race-free)

  k_prep <<<dim3(NPTS / 64 + 1, NB), 256, 0, stream>>>(x, W1, b1, W2, b2,
                                                       XT, XH, XL, SQ, SQN,
                                                       GH, GL, BB);
  k_knn  <<<dim3(NPTS / (KNN_T / 4), NQ, NB), KNN_T, 0, stream>>>(XH, SQN, PART);
  k_mr   <<<dim3(NPT_ALL / 8), 256, 0, stream>>>(PART, XT, SQ, KNN);
  k_pq   <<<dim3(NPT_ALL / 64), 256, 0, stream>>>(XH, XL, GH, GL, BB, Pm, Qm);
  k_out  <<<dim3(NPTS / 64, NB), 512, 0, stream>>>(Pm, Qm, KNN, out);
}